// Round 13
// baseline (195.366 us; speedup 1.0000x reference)
//
#include <hip/hip_runtime.h>
#include <hip/hip_bf16.h>
#include <stdint.h>

typedef __bf16 bf16;
typedef __bf16 bf16x8 __attribute__((ext_vector_type(8)));
typedef float f32x4 __attribute__((ext_vector_type(4)));

#define TAU (1.0f/30.0f)

#define NB 32
#define CI 256
#define CO 256
#define HH 64
#define WW 64
#define HID 64

// wn fragment-linear layout: [n][c(8 ci-chunks)][kk(9)][cbg(16)][lane(64)][j(8)]
#define WN_ELEMS ((size_t)NB*8*9*16*512)
#define WN_BYTES (WN_ELEMS*2)
// xb padded layout: [n][cg(32)][hr(66)][wl(66)][j(8)] bf16, margins (hr/wl = 0 or 65) zeroed
#define PLANE_E 34848          // 66*66*8
#define XB_ELEMS ((size_t)NB*32*PLANE_E)
#define XB_BYTES (XB_ELEMS*2)  // 71.37 MB

__device__ __forceinline__ void async16(void* lds_uniform_base, const void* g_perlane) {
  __builtin_amdgcn_global_load_lds(
      (const __attribute__((address_space(1))) uint32_t*)g_perlane,
      (__attribute__((address_space(3))) uint32_t*)lds_uniform_base, 16, 0, 0);
}

// Fused fp32->bf16 repack (padded layout) + global average pool. float4-vectorized:
// 4 iters x (8 x 16B loads + 4 x 16B contiguous stores) per thread.
__global__ void cvt_pool_kernel(const float* __restrict__ x, bf16* __restrict__ xb,
                                float* __restrict__ pooled) {
  const int cg = blockIdx.x, n = blockIdx.y, tid = threadIdx.x;
  const float* base = x + ((size_t)n*CI + cg*8)*4096;
  bf16* ob = xb + ((size_t)n*32 + cg)*PLANE_E;
  // zero the 260 margin slots (hr=0, hr=65, wl=0, wl=65)
  for (int i = tid; i < 260; i += 256) {
    int hr, wl;
    if (i < 66)       { hr = 0;       wl = i; }
    else if (i < 132) { hr = 65;      wl = i - 66; }
    else if (i < 196) { hr = i - 131; wl = 0; }
    else              { hr = i - 195; wl = 65; }
    *(int4*)(ob + ((size_t)hr*66 + wl)*8) = int4{0,0,0,0};
  }
  float s[8];
#pragma unroll
  for (int j = 0; j < 8; ++j) s[j] = 0.f;
#pragma unroll
  for (int it = 0; it < 4; ++it) {
    int pos = (it*256 + tid) * 4;      // 0..4092, multiple of 4; w+3 <= 63
    int h = pos >> 6, w = pos & 63;
    float4 v[8];
#pragma unroll
    for (int j = 0; j < 8; ++j) {
      v[j] = *(const float4*)(base + (size_t)j*4096 + pos);
      s[j] += v[j].x + v[j].y + v[j].z + v[j].w;
    }
    bf16* orow = ob + ((size_t)(h+1)*66 + (w+1))*8;
#pragma unroll
    for (int k = 0; k < 4; ++k) {
      bf16x8 o;
      o[0] = (bf16)(k==0?v[0].x:k==1?v[0].y:k==2?v[0].z:v[0].w);
      o[1] = (bf16)(k==0?v[1].x:k==1?v[1].y:k==2?v[1].z:v[1].w);
      o[2] = (bf16)(k==0?v[2].x:k==1?v[2].y:k==2?v[2].z:v[2].w);
      o[3] = (bf16)(k==0?v[3].x:k==1?v[3].y:k==2?v[3].z:v[3].w);
      o[4] = (bf16)(k==0?v[4].x:k==1?v[4].y:k==2?v[4].z:v[4].w);
      o[5] = (bf16)(k==0?v[5].x:k==1?v[5].y:k==2?v[5].z:v[5].w);
      o[6] = (bf16)(k==0?v[6].x:k==1?v[6].y:k==2?v[6].z:v[6].w);
      o[7] = (bf16)(k==0?v[7].x:k==1?v[7].y:k==2?v[7].z:v[7].w);
      *(bf16x8*)(orow + (size_t)k*8) = o;
    }
  }
  __shared__ float red[4][8];
#pragma unroll
  for (int j = 0; j < 8; ++j)
#pragma unroll
    for (int off = 32; off; off >>= 1) s[j] += __shfl_xor(s[j], off);
  int wv = tid >> 6, lane = tid & 63;
  if (lane == 0)
#pragma unroll
    for (int j = 0; j < 8; ++j) red[wv][j] = s[j];
  __syncthreads();
  if (tid < 8) {
    float t = red[0][tid] + red[1][tid] + red[2][tid] + red[3][tid];
    pooled[n*CI + cg*8 + tid] = t * (1.0f/4096.0f);
  }
}

__global__ void attn_kernel(const float* __restrict__ pooled,
                            const float* __restrict__ w1, const float* __restrict__ b1,
                            const float* __restrict__ w2, const float* __restrict__ b2,
                            float* __restrict__ pi) {
  int n = blockIdx.x, h = threadIdx.x;        // 64 threads
  __shared__ float hm[HID];
  __shared__ float lgs[4];
  const float* pr = pooled + n*CI;
  float s = b1[h];
  for (int c = 0; c < CI; ++c) s += pr[c] * w1[h*CI + c];
  hm[h] = s > 0.f ? s : 0.f;
  __syncthreads();
  if (h < 4) {
    float lg = b2[h];
    for (int k = 0; k < HID; ++k) lg += hm[k] * w2[h*HID + k];
    lgs[h] = lg * TAU;
  }
  __syncthreads();
  if (h == 0) {
    float mx = fmaxf(fmaxf(lgs[0], lgs[1]), fmaxf(lgs[2], lgs[3]));
    float e0 = expf(lgs[0]-mx), e1 = expf(lgs[1]-mx), e2 = expf(lgs[2]-mx), e3 = expf(lgs[3]-mx);
    float inv = 1.f / (e0+e1+e2+e3);
    pi[n*4+0] = e0*inv; pi[n*4+1] = e1*inv; pi[n*4+2] = e2*inv; pi[n*4+3] = e3*inv;
  }
}

__global__ void agg_kernel(const float* __restrict__ Wbank, const float* __restrict__ pi,
                           bf16* __restrict__ wn) {
  int wid = blockIdx.x * 4 + (threadIdx.x >> 6);   // 0..1151
  int lane = threadIdx.x & 63;
  int c = wid / 144;
  int rem = wid - c*144;
  int kk = rem >> 4;
  int cbg = rem & 15;
  int co  = cbg*16 + (lane & 15);
  int ci0 = c*32 + (lane >> 4)*8;
  float w[4][8];
#pragma unroll
  for (int m = 0; m < 4; ++m)
#pragma unroll
    for (int j = 0; j < 8; ++j)
      w[m][j] = Wbank[(size_t)((co*4 + m)*256 + ci0 + j)*9 + kk];
  for (int n = 0; n < NB; ++n) {
    float p0 = pi[n*4+0], p1 = pi[n*4+1], p2 = pi[n*4+2], p3 = pi[n*4+3];
    bf16x8 o;
#pragma unroll
    for (int j = 0; j < 8; ++j)
      o[j] = (bf16)(p0*w[0][j] + p1*w[1][j] + p2*w[2][j] + p3*w[3][j]);
    *(bf16x8*)(wn + ((size_t)n*1152 + c*144 + kk*16 + cbg)*512 + lane*8) = o;
  }
}

// Conv R13 == R12 (frozen): 8 rows x 64 co, 4 waves; A dbuf LDS via DMA,
// B global->VGPR distance-2, raw s_barrier between chunks.
#define WA_E (9*4*512)        // 18432 el = 36864 B per buffer

#define LDG(st, rr, kxx, cc) { _Pragma("unroll") \
  for (int f = 0; f < 4; ++f) \
    S[st][f] = *(const bf16x8*)(xu + ((size_t)(cc)*139392 + (rr)*528 + f*128 + (kxx)*8)); }

#define MM(kkv, lo, hi) { \
  __builtin_amdgcn_s_setprio(1); \
  _Pragma("unroll") for (int cb = 0; cb < 4; ++cb) { \
    bf16x8 afr = *(const bf16x8*)(&wab[(kkv)*2048 + cb*512 + lane*8]); \
    _Pragma("unroll") for (int f = 0; f < 4; ++f) { \
      acc[0][cb][f] = __builtin_amdgcn_mfma_f32_16x16x32_bf16(afr, lo[f], acc[0][cb][f], 0,0,0); \
      acc[1][cb][f] = __builtin_amdgcn_mfma_f32_16x16x32_bf16(afr, hi[f], acc[1][cb][f], 0,0,0); \
    } } \
  __builtin_amdgcn_s_setprio(0); }

#define STAGE_W(cc, b) { const bf16* seg = wnb + (size_t)(cc)*73728; \
  _Pragma("unroll") for (int kk = 0; kk < 9; ++kk) \
    async16(&wa[b][kk*2048 + wv*512], seg + (size_t)kk*8192); }

#define RAW_BAR() { __builtin_amdgcn_sched_barrier(0); \
                    __builtin_amdgcn_s_barrier(); \
                    __builtin_amdgcn_sched_barrier(0); }

__global__ __launch_bounds__(256, 2)
void conv_kernel(const bf16* __restrict__ xb, const bf16* __restrict__ wn,
                 const float* __restrict__ pi, const float* __restrict__ Bbank,
                 float* __restrict__ y) {
  __shared__ __align__(16) bf16 wa[2][WA_E];   // 73728 B
  __shared__ float bns[64];
  const int tid = threadIdx.x;
  const int wv = tid >> 6, lane = tid & 63;
  const int l = lane & 15, u = lane >> 4;
  // XCD-aware swizzle (bijective, 1024 % 8 == 0): each XCD owns 4 consecutive n's.
  const int flat = blockIdx.x;
  const int wid = ((flat & 7) << 7) + (flat >> 3);
  const int n   = wid >> 5;
  const int hwb = (wid >> 2) & 7;
  const int cot = wid & 3;
  const int h0 = hwb * 8;

  const bf16* wnb = wn + (size_t)n*1152*512 + (size_t)(cot*4 + wv)*512 + lane*8;
  const bf16* xu = xb + (((size_t)(n*32 + u)*66 + (h0 + wv*2))*66 + l)*8;

  bf16x8 S[4][4];
  STAGE_W(0, 0);                // 9 DMAs for chunk 0
  LDG(0, 0, 0, 0) LDG(1, 1, 0, 0)   // chunk-0 S0,S1 prologue

  if (tid < 64) {
    int co = cot*64 + tid;
    bns[tid] = pi[n*4+0]*Bbank[co*4+0] + pi[n*4+1]*Bbank[co*4+1]
             + pi[n*4+2]*Bbank[co*4+2] + pi[n*4+3]*Bbank[co*4+3];
  }

  f32x4 acc[2][4][4];
#pragma unroll
  for (int o = 0; o < 2; ++o)
#pragma unroll
    for (int a = 0; a < 4; ++a)
#pragma unroll
      for (int b = 0; b < 4; ++b)
#pragma unroll
        for (int k = 0; k < 4; ++k) acc[o][a][b][k] = 0.f;

  __syncthreads();              // ONE full drain: wa[0] + S0,S1 landed, bns visible

  for (int c = 0; c < 8; ++c) {
    if (c) RAW_BAR();           // raw barrier: prefetches stay in flight (counted waits)
    LDG(2, 2, 0, c) LDG(3, 3, 0, c)
    if (c < 7) STAGE_W(c + 1, (c + 1) & 1);
    const bf16* wab = wa[c & 1];
    const int cp = (c < 7) ? c + 1 : 7;
    MM(0, S[0], S[1])
    MM(3, S[1], S[2]) LDG(0, 0, 1, c) LDG(1, 1, 1, c)
    MM(6, S[2], S[3]) LDG(2, 2, 1, c)
    MM(1, S[0], S[1]) LDG(3, 3, 1, c)
    MM(4, S[1], S[2]) LDG(0, 0, 2, c) LDG(1, 1, 2, c)
    MM(7, S[2], S[3]) LDG(2, 2, 2, c)
    MM(2, S[0], S[1]) LDG(3, 3, 2, c)
    MM(5, S[1], S[2]) LDG(0, 0, 0, cp) LDG(1, 1, 0, cp)
    MM(8, S[2], S[3])
  }
  // epilogue: D row=(lane>>4)*4+reg -> co, col=lane&15 -> w
#pragma unroll
  for (int o = 0; o < 2; ++o) {
    const int h = h0 + wv*2 + o;
#pragma unroll
    for (int cb = 0; cb < 4; ++cb) {
#pragma unroll
      for (int f = 0; f < 4; ++f) {
        const int wcol = f*16 + l;
#pragma unroll
        for (int r4 = 0; r4 < 4; ++r4) {
          const int col = cb*16 + u*4 + r4;
          y[(((size_t)n*CO + cot*64 + col)*HH + h)*WW + wcol] = acc[o][cb][f][r4] + bns[col];
        }
      }
    }
  }
}

extern "C" void kernel_launch(void* const* d_in, const int* in_sizes, int n_in,
                              void* d_out, int out_size, void* d_ws, size_t ws_size,
                              hipStream_t stream) {
  const float* x     = (const float*)d_in[0];
  const float* Wbank = (const float*)d_in[1];
  const float* Bbank = (const float*)d_in[2];
  const float* w1    = (const float*)d_in[3];
  const float* b1    = (const float*)d_in[4];
  const float* w2    = (const float*)d_in[5];
  const float* b2    = (const float*)d_in[6];
  float* y = (float*)d_out;

  bf16*  wn     = (bf16*)d_ws;                                  // 37.75 MB
  bf16*  xb     = (bf16*)((char*)d_ws + WN_BYTES);              // 71.37 MB (padded)
  float* pooled = (float*)((char*)d_ws + WN_BYTES + XB_BYTES);  // 32 KB
  float* pi     = pooled + NB*CI;                               // 512 B

  dim3 cg(32, NB);
  cvt_pool_kernel<<<cg, 256, 0, stream>>>(x, xb, pooled);
  attn_kernel<<<NB, HID, 0, stream>>>(pooled, w1, b1, w2, b2, pi);
  agg_kernel<<<288, 256, 0, stream>>>(Wbank, pi, wn);
  conv_kernel<<<1024, 256, 0, stream>>>(xb, wn, pi, Bbank, y);
}

// Round 14
// 189.119 us; speedup vs baseline: 1.0330x; 1.0330x over previous
//
#include <hip/hip_runtime.h>
#include <hip/hip_bf16.h>
#include <stdint.h>

typedef __bf16 bf16;
typedef __bf16 bf16x8 __attribute__((ext_vector_type(8)));
typedef float f32x4 __attribute__((ext_vector_type(4)));

#define TAU (1.0f/30.0f)

#define NB 32
#define CI 256
#define CO 256
#define HH 64
#define WW 64
#define HID 64

// wn fragment-linear layout: [n][c(8 ci-chunks)][kk(9)][cbg(16)][lane(64)][j(8)]
#define WN_ELEMS ((size_t)NB*8*9*16*512)
#define WN_BYTES (WN_ELEMS*2)
// xb packed layout: [n][cg(32 ci-groups of 8)][h(64)][w(64)][j(8)] bf16
#define XB_ELEMS ((size_t)NB*32*64*64*8)
#define XB_BYTES (XB_ELEMS*2)

__device__ __forceinline__ void async16(void* lds_uniform_base, const void* g_perlane) {
  __builtin_amdgcn_global_load_lds(
      (const __attribute__((address_space(1))) uint32_t*)g_perlane,
      (__attribute__((address_space(3))) uint32_t*)lds_uniform_base, 16, 0, 0);
}

// Fused fp32->bf16 repack + global average pool (scalar loads: BW-bound already;
// R13 showed float4+select packing regresses ~5 us of VALU).
__global__ void cvt_pool_kernel(const float* __restrict__ x, bf16* __restrict__ xb,
                                float* __restrict__ pooled) {
  const int cg = blockIdx.x, n = blockIdx.y, tid = threadIdx.x;
  const float* base = x + ((size_t)n*CI + cg*8)*4096;
  bf16* ob = xb + ((size_t)n*32 + cg)*4096*8;
  float s[8];
#pragma unroll
  for (int j = 0; j < 8; ++j) s[j] = 0.f;
  for (int it = 0; it < 16; ++it) {
    int pos = it*256 + tid;
    bf16x8 o;
#pragma unroll
    for (int j = 0; j < 8; ++j) {
      float v = base[(size_t)j*4096 + pos];
      s[j] += v;
      o[j] = (bf16)v;
    }
    *(bf16x8*)(ob + (size_t)pos*8) = o;
  }
  __shared__ float red[4][8];
#pragma unroll
  for (int j = 0; j < 8; ++j)
#pragma unroll
    for (int off = 32; off; off >>= 1) s[j] += __shfl_xor(s[j], off);
  int wv = tid >> 6, lane = tid & 63;
  if (lane == 0)
#pragma unroll
    for (int j = 0; j < 8; ++j) red[wv][j] = s[j];
  __syncthreads();
  if (tid < 8) {
    float t = red[0][tid] + red[1][tid] + red[2][tid] + red[3][tid];
    pooled[n*CI + cg*8 + tid] = t * (1.0f/4096.0f);
  }
}

__global__ void attn_kernel(const float* __restrict__ pooled,
                            const float* __restrict__ w1, const float* __restrict__ b1,
                            const float* __restrict__ w2, const float* __restrict__ b2,
                            float* __restrict__ pi) {
  int n = blockIdx.x, h = threadIdx.x;        // 64 threads
  __shared__ float hm[HID];
  __shared__ float lgs[4];
  const float* pr = pooled + n*CI;
  float s = b1[h];
  for (int c = 0; c < CI; ++c) s += pr[c] * w1[h*CI + c];
  hm[h] = s > 0.f ? s : 0.f;
  __syncthreads();
  if (h < 4) {
    float lg = b2[h];
    for (int k = 0; k < HID; ++k) lg += hm[k] * w2[h*HID + k];
    lgs[h] = lg * TAU;
  }
  __syncthreads();
  if (h == 0) {
    float mx = fmaxf(fmaxf(lgs[0], lgs[1]), fmaxf(lgs[2], lgs[3]));
    float e0 = expf(lgs[0]-mx), e1 = expf(lgs[1]-mx), e2 = expf(lgs[2]-mx), e3 = expf(lgs[3]-mx);
    float inv = 1.f / (e0+e1+e2+e3);
    pi[n*4+0] = e0*inv; pi[n*4+1] = e1*inv; pi[n*4+2] = e2*inv; pi[n*4+3] = e3*inv;
  }
}

__global__ void agg_kernel(const float* __restrict__ Wbank, const float* __restrict__ pi,
                           bf16* __restrict__ wn) {
  int wid = blockIdx.x * 4 + (threadIdx.x >> 6);   // 0..1151
  int lane = threadIdx.x & 63;
  int c = wid / 144;
  int rem = wid - c*144;
  int kk = rem >> 4;
  int cbg = rem & 15;
  int co  = cbg*16 + (lane & 15);
  int ci0 = c*32 + (lane >> 4)*8;
  float w[4][8];
#pragma unroll
  for (int m = 0; m < 4; ++m)
#pragma unroll
    for (int j = 0; j < 8; ++j)
      w[m][j] = Wbank[(size_t)((co*4 + m)*256 + ci0 + j)*9 + kk];
  for (int n = 0; n < NB; ++n) {
    float p0 = pi[n*4+0], p1 = pi[n*4+1], p2 = pi[n*4+2], p3 = pi[n*4+3];
    bf16x8 o;
#pragma unroll
    for (int j = 0; j < 8; ++j)
      o[j] = (bf16)(p0*w[0][j] + p1*w[1][j] + p2*w[2][j] + p3*w[3][j]);
    *(bf16x8*)(wn + ((size_t)n*1152 + c*144 + kk*16 + cbg)*512 + lane*8) = o;
  }
}

// Conv (R6 structure + g-plane bank pad): block = 8 rows x 64 co; 4 waves, wave wv
// owns rows h0+wv*2, h0+wv*2+1. Weights(c+1) global->VGPR during compute(c) (T14),
// ds_write at chunk boundary; x DMAs drain at barrier2.
// xs: [g(4)][r(10: h0-1..h0+8)][wl(66)][j(8)] + 8-el pad per g-plane so the four
// u-groups land on distinct bank offsets {0,20,8,28} -> conflict-free ds_read_b128.
#define XROWS 10
#define XW 66
#define XSG (XROWS*XW*8 + 8)  // 5288 el per g-plane (16B inter-plane pad)
#define XS_E (4*XSG)          // 21152 el = 42304 B
#define WA_E (9*4*512)        // 18432 el = 36864 B

__global__ __launch_bounds__(256, 2)
void conv_kernel(const bf16* __restrict__ xb, const bf16* __restrict__ wn,
                 const float* __restrict__ pi, const float* __restrict__ Bbank,
                 float* __restrict__ y) {
  __shared__ __align__(16) bf16 xs[XS_E];
  __shared__ __align__(16) bf16 wa[WA_E];
  __shared__ float bns[64];
  const int tid = threadIdx.x;
  const int wv = tid >> 6, lane = tid & 63;
  const int l = lane & 15, u = lane >> 4;
  // XCD-aware swizzle (bijective, 1024 % 8 == 0): each XCD owns 4 consecutive n's.
  const int flat = blockIdx.x;
  const int wid = ((flat & 7) << 7) + (flat >> 3);
  const int n   = wid >> 5;
  const int hwb = (wid >> 2) & 7;
  const int cot = wid & 3;
  const int h0 = hwb * 8;

  const bf16* wnb = wn + (size_t)n*1152*512 + (size_t)(cot*4 + wv)*512 + lane*8;
  const bf16* xgb = xb + (size_t)n*32*4096*8 + lane*8;

  bf16x8 wstg[9];
  auto LOADW = [&](int c) {
    const bf16* seg = wnb + (size_t)c*144*512;
#pragma unroll
    for (int kk = 0; kk < 9; ++kk)
      wstg[kk] = *(const bf16x8*)(seg + (size_t)kk*16*512);
  };

  LOADW(0);                     // in flight under prologue

  // one-time zero: halo cols (wl=0,65) + OOB rows + pads stay zero forever
  for (int i = tid; i < XS_E/8; i += 256) ((int4*)xs)[i] = int4{0,0,0,0};
  if (tid < 64) {
    int co = cot*64 + tid;
    bns[tid] = pi[n*4+0]*Bbank[co*4+0] + pi[n*4+1]*Bbank[co*4+1]
             + pi[n*4+2]*Bbank[co*4+2] + pi[n*4+3]*Bbank[co*4+3];
  }

  f32x4 acc[2][4][4];
#pragma unroll
  for (int o = 0; o < 2; ++o)
#pragma unroll
    for (int a = 0; a < 4; ++a)
#pragma unroll
      for (int b = 0; b < 4; ++b)
#pragma unroll
        for (int k = 0; k < 4; ++k) acc[o][a][b][k] = 0.f;

  for (int c = 0; c < 8; ++c) {
    __syncthreads();            // all waves done reading xs/wa of chunk c-1
    // issue x DMAs for chunk c (drain at next barrier)
    {
      const bf16* xg = xgb + (size_t)(c*4 + wv)*4096*8;
#pragma unroll
      for (int r = 0; r < XROWS; ++r) {
        int hp = h0 - 1 + r;
        if (hp >= 0 && hp < HH)
          async16(&xs[wv*XSG + (r*XW + 1)*8], xg + (size_t)hp*64*8);
      }
    }
    // write staged weights (loaded during previous compute)
#pragma unroll
    for (int kk = 0; kk < 9; ++kk)
      *(int4*)(&wa[kk*2048 + wv*512 + lane*8]) = *(int4*)&wstg[kk];
    __syncthreads();            // vm (x DMA) + lgkm (wa writes) drained
    if (c < 7) LOADW(c + 1);    // weight latency hides under compute

    // compute: rolling 2-row B window to cap VGPR liveness
    auto LD = [&](int rr, int f, int kx) {
      return *(const bf16x8*)(&xs[u*XSG + ((wv*2 + rr)*XW + f*16 + l + kx)*8]);
    };
    auto MM = [&](int ky, int kx, bf16x8 (&lo)[4], bf16x8 (&hi)[4]) {
      const int kk = ky*3 + kx;
      __builtin_amdgcn_s_setprio(1);
#pragma unroll
      for (int cb = 0; cb < 4; ++cb) {
        bf16x8 afr = *(const bf16x8*)(&wa[kk*2048 + cb*512 + lane*8]);
#pragma unroll
        for (int f = 0; f < 4; ++f) {
          acc[0][cb][f] = __builtin_amdgcn_mfma_f32_16x16x32_bf16(afr, lo[f], acc[0][cb][f], 0, 0, 0);
          acc[1][cb][f] = __builtin_amdgcn_mfma_f32_16x16x32_bf16(afr, hi[f], acc[1][cb][f], 0, 0, 0);
        }
      }
      __builtin_amdgcn_s_setprio(0);
    };
#pragma unroll
    for (int kx = 0; kx < 3; ++kx) {
      bf16x8 rA[4], rB[4];
#pragma unroll
      for (int f = 0; f < 4; ++f) { rA[f] = LD(0, f, kx); rB[f] = LD(1, f, kx); }
      MM(0, kx, rA, rB);        // ky=0: rows 0,1
#pragma unroll
      for (int f = 0; f < 4; ++f) rA[f] = LD(2, f, kx);
      MM(1, kx, rB, rA);        // ky=1: rows 1,2
#pragma unroll
      for (int f = 0; f < 4; ++f) rB[f] = LD(3, f, kx);
      MM(2, kx, rA, rB);        // ky=2: rows 2,3
    }
  }
  // epilogue: D row=(lane>>4)*4+reg -> co, col=lane&15 -> w
#pragma unroll
  for (int o = 0; o < 2; ++o) {
    const int h = h0 + wv*2 + o;
#pragma unroll
    for (int cb = 0; cb < 4; ++cb) {
#pragma unroll
      for (int f = 0; f < 4; ++f) {
        const int wcol = f*16 + l;
#pragma unroll
        for (int r4 = 0; r4 < 4; ++r4) {
          const int col = cb*16 + u*4 + r4;
          y[(((size_t)n*CO + cot*64 + col)*HH + h)*WW + wcol] = acc[o][cb][f][r4] + bns[col];
        }
      }
    }
  }
}

extern "C" void kernel_launch(void* const* d_in, const int* in_sizes, int n_in,
                              void* d_out, int out_size, void* d_ws, size_t ws_size,
                              hipStream_t stream) {
  const float* x     = (const float*)d_in[0];
  const float* Wbank = (const float*)d_in[1];
  const float* Bbank = (const float*)d_in[2];
  const float* w1    = (const float*)d_in[3];
  const float* b1    = (const float*)d_in[4];
  const float* w2    = (const float*)d_in[5];
  const float* b2    = (const float*)d_in[6];
  float* y = (float*)d_out;

  bf16*  wn     = (bf16*)d_ws;                                  // 37.75 MB
  bf16*  xb     = (bf16*)((char*)d_ws + WN_BYTES);              // 67.1 MB
  float* pooled = (float*)((char*)d_ws + WN_BYTES + XB_BYTES);  // 32 KB
  float* pi     = pooled + NB*CI;                               // 512 B

  dim3 cg(32, NB);
  cvt_pool_kernel<<<cg, 256, 0, stream>>>(x, xb, pooled);
  attn_kernel<<<NB, HID, 0, stream>>>(pooled, w1, b1, w2, b2, pi);
  agg_kernel<<<288, 256, 0, stream>>>(Wbank, pi, wn);
  conv_kernel<<<1024, 256, 0, stream>>>(xb, wn, pi, Bbank, y);
}